// Round 13
// baseline (194.640 us; speedup 1.0000x reference)
//
#include <hip/hip_runtime.h>

// pred_vol shape (1,1,64,512,512) fp32; threshold 0.5; window 9 (R=4).
// Identity: thr is monotone and the window contains the center, so
// reference output == (c > 0.5 && c == max9x9x9_raw(x)) ? c : 0.
static constexpr int Dd = 64;
static constexpr int Hh = 512;
static constexpr int Ww = 512;
static constexpr int RAD = 4;
static constexpr float THRESH_V = 0.5f;
static constexpr int W4 = Ww / 4;          // 128 float4 per row
static constexpr int PLANE4 = Hh * W4;     // 65536 float4 per D-plane

static constexpr int TH = 4;               // output h-rows per block
static constexpr int DC = 16;              // output d-planes per block (r10 best)
static constexpr int ROWS = TH + 2 * RAD;  // 12 staged rows per plane
static constexpr int STEPS = DC + 2 * RAD; // 24 d-steps per block
static constexpr int NBLK = (Hh / TH) * (Dd / DC);  // 512 blocks (2/CU)

typedef float nf4 __attribute__((ext_vector_type(4)));  // native vec for nt-store

__device__ __forceinline__ float4 f4max(float4 a, float4 b) {
    return make_float4(fmaxf(a.x, b.x), fmaxf(a.y, b.y), fmaxf(a.z, b.z), fmaxf(a.w, b.w));
}
__device__ __forceinline__ int iclamp(int v, int lo, int hi) {
    return v < lo ? lo : (v > hi ? hi : v);
}

// DPP direction semantics (per the canonical GCN scan idiom, which uses
// row_shr:1 to accumulate from LOWER lanes): *_shr:N -> lane i reads lane
// i-N; *_shl:N -> lane i reads lane i+N. Round 12 had these swapped.
__device__ __forceinline__ float dpp_from_left(float v) {   // lane i <- lane i-1
    int s = __float_as_int(v);
    return __int_as_float(__builtin_amdgcn_update_dpp(s, s, 0x138, 0xF, 0xF, false));
}
__device__ __forceinline__ float dpp_from_right(float v) {  // lane i <- lane i+1
    int s = __float_as_int(v);
    return __int_as_float(__builtin_amdgcn_update_dpp(s, s, 0x130, 0xF, 0xF, false));
}

// LDS-only barrier: __syncthreads() emits s_waitcnt vmcnt(0) lgkmcnt(0) +
// s_barrier, draining the cross-step global prefetch. We only need LDS
// ordering, so wait lgkmcnt(0) only and let VMEM stay in flight (r10: -9 µs).
#define LDS_BARRIER() asm volatile("s_waitcnt lgkmcnt(0)\n\ts_barrier" ::: "memory")

// (512,2): CUDA-style min-blocks semantics -> 2 blocks/CU, 128-VGPR cap.
__global__ __launch_bounds__(512, 2)
void fused_nms_k(const float4* __restrict__ x4, float4* __restrict__ o4) {
    // double-buffered staging of per-plane W-max rows: 2 * 12 * 128 * 16B = 48 KB
    __shared__ float4 buf[2][ROWS * W4];

    const int tid  = threadIdx.x;
    const int lane = tid & 63;
    const int w4   = tid & (W4 - 1);              // 0..127
    const int hr   = tid >> 7;                    // 0..3
    // XCD swizzle: band = blockIdx&7 -> h-band of 64 rows stays on one XCD's L2
    const int b    = blockIdx.x;
    const int band = b & 7;
    const int rest = b >> 3;                      // 0..63
    const int ht   = band * 16 + (rest & 15);     // 0..127
    const int dc   = rest >> 4;                   // 0..3
    const int h0   = ht * TH;
    const int d0   = dc * DC;

    const bool l0  = (lane == 0);
    const bool l63 = (lane == 63);
    const int colm = w4 ? w4 - 1 : 0;
    const int colp = (w4 < W4 - 1) ? w4 + 1 : W4 - 1;
    const int hcol = l0 ? colm : colp;            // only lanes 0/63 use it

    // per-thread element offsets within a plane: 3 self rows + 3 halo slots
    int off[3], hoff[3];
#pragma unroll
    for (int k = 0; k < 3; ++k) {
        int gh = iclamp(h0 - RAD + hr + 4 * k, 0, Hh - 1);
        off[k]  = gh * W4 + w4;
        hoff[k] = gh * W4 + hcol;
    }
    const int outrow = (h0 + hr) * W4 + w4;

    // Slot ring: R[t % 8] holds H-max of plane t, overwritten AFTER use.
    float4 R[8];
    float4 L[3], HL[3];
    {   // preload plane for t=0
        const float4* pl = x4 + (size_t)iclamp(d0 - RAD, 0, Dd - 1) * PLANE4;
#pragma unroll
        for (int k = 0; k < 3; ++k) L[k] = pl[off[k]];
#pragma unroll
        for (int k = 0; k < 3; ++k) HL[k] = L[k];   // defined on all lanes
        if (l0 || l63) {
#pragma unroll
            for (int k = 0; k < 3; ++k) HL[k] = pl[hoff[k]];
        }
    }

    // 9-wide W-window max for this lane's 4 columns, neighbors via DPP.
    // Own cols 4i..4i+3; o[j] covers [4i+j-4, 4i+j+4]:
    //   o.x = max(left.max4, own.max4(core), right.x)
    //   o.y = max(left.suf1, core, right.pre1)  etc.
    auto wmax_row = [&](float4 a, float4 ah) -> float4 {
        float suf3 = a.w;
        float suf2 = fmaxf(a.z, suf3);
        float suf1 = fmaxf(a.y, suf2);
        float core = fmaxf(a.x, suf1);
        float pre0 = a.x;
        float pre1 = fmaxf(pre0, a.y);
        float pre2 = fmaxf(pre1, a.z);
        float Ls0 = dpp_from_left(core), Ls1 = dpp_from_left(suf1);
        float Ls2 = dpp_from_left(suf2), Ls3 = dpp_from_left(suf3);
        float Rp0 = dpp_from_right(pre0), Rp1 = dpp_from_right(pre1);
        float Rp2 = dpp_from_right(pre2), Rp3 = dpp_from_right(core);
        // halo chains (meaningful only on lanes 0/63; garbage elsewhere is discarded)
        float hs3 = ah.w, hs2 = fmaxf(ah.z, hs3), hs1 = fmaxf(ah.y, hs2), hs0 = fmaxf(ah.x, hs1);
        float hp0 = ah.x, hp1 = fmaxf(hp0, ah.y), hp2 = fmaxf(hp1, ah.z);
        Ls0 = l0 ? hs0 : Ls0;  Ls1 = l0 ? hs1 : Ls1;
        Ls2 = l0 ? hs2 : Ls2;  Ls3 = l0 ? hs3 : Ls3;
        Rp0 = l63 ? hp0 : Rp0; Rp1 = l63 ? hp1 : Rp1;
        Rp2 = l63 ? hp2 : Rp2; Rp3 = l63 ? hs0 : Rp3;
        float4 o;
        o.x = fmaxf(Ls0, fmaxf(core, Rp0));
        o.y = fmaxf(Ls1, fmaxf(core, Rp1));
        o.z = fmaxf(Ls2, fmaxf(core, Rp2));
        o.w = fmaxf(Ls3, fmaxf(core, Rp3));
        return o;
    };

    // One d-step. slot/par/emit compile-time at every call site.
    auto body = [&](int t, int slot, int par, bool emit) {
        float4* B = buf[par];
        // (1) W-max of the 3 staged rows — consumes L/HL (vmcnt wait lands here)
        float4 o0 = wmax_row(L[0], HL[0]);
        float4 o1 = wmax_row(L[1], HL[1]);
        float4 o2 = wmax_row(L[2], HL[2]);
        // (2) L/HL dead — issue next plane's loads + this step's center NOW,
        //     BEFORE the weak barrier, so they stay in flight all step.
        float4 cen;
        if (emit) cen = x4[(size_t)(d0 + t - 2 * RAD) * PLANE4 + outrow];
        if (t + 1 < STEPS) {
            const int gd = iclamp(d0 - RAD + t + 1, 0, Dd - 1);
            const float4* pl = x4 + (size_t)gd * PLANE4;
#pragma unroll
            for (int k = 0; k < 3; ++k) L[k] = pl[off[k]];
            if (l0 || l63) {
#pragma unroll
                for (int k = 0; k < 3; ++k) HL[k] = pl[hoff[k]];
            }
        }
        // (3) stage + LDS-only barrier (globals NOT drained)
        B[0 * 512 + tid] = o0;
        B[1 * 512 + tid] = o1;
        B[2 * 512 + tid] = o2;
        LDS_BARRIER();

        // (4) H-max over 9 staged rows at this thread's column
        const float4* Bb = B + hr * W4 + w4;
        float4 m = Bb[0];
#pragma unroll
        for (int i = 1; i < 9; ++i) m = f4max(m, Bb[i * W4]);

        // (5) emit: D-window-9 = max(8 ring slots, current m)
        if (emit) {
            float4 mm = m;
#pragma unroll
            for (int i = 0; i < 8; ++i) mm = f4max(mm, R[i]);
            nf4 q;
            q.x = (cen.x > THRESH_V && cen.x == mm.x) ? cen.x : 0.0f;
            q.y = (cen.y > THRESH_V && cen.y == mm.y) ? cen.y : 0.0f;
            q.z = (cen.z > THRESH_V && cen.z == mm.z) ? cen.z : 0.0f;
            q.w = (cen.w > THRESH_V && cen.w == mm.w) ? cen.w : 0.0f;
            __builtin_nontemporal_store(
                q, (nf4*)&o4[(size_t)(d0 + t - 2 * RAD) * PLANE4 + outrow]);
        }
        R[slot] = m;   // overwrite after use
    };

    // Prologue: fill ring with planes d0-4 .. d0+3 (clamped), no outputs.
#pragma unroll
    for (int t = 0; t < 8; ++t) body(t, t, t & 1, false);
    // Main: 16 emitting steps, unroll 8 so slot indices are static.
    for (int tb = 8; tb < STEPS; tb += 8) {
#pragma unroll
        for (int j = 0; j < 8; ++j) body(tb + j, j, j & 1, true);
    }
}

extern "C" void kernel_launch(void* const* d_in, const int* in_sizes, int n_in,
                              void* d_out, int out_size, void* d_ws, size_t ws_size,
                              hipStream_t stream) {
    const float4* x4 = (const float4*)d_in[0];
    float4* out4 = (float4*)d_out;
    (void)d_ws; (void)ws_size; (void)in_sizes; (void)n_in; (void)out_size;
    fused_nms_k<<<dim3(NBLK), dim3(512), 0, stream>>>(x4, out4);
}

// Round 14
// 171.992 us; speedup vs baseline: 1.1317x; 1.1317x over previous
//
#include <hip/hip_runtime.h>

// pred_vol shape (1,1,64,512,512) fp32; threshold 0.5; window 9 (R=4).
// Identity: thr is monotone and the window contains the center, so
// reference output == (c > 0.5 && c == max9x9x9_raw(x)) ? c : 0.
static constexpr int Dd = 64;
static constexpr int Hh = 512;
static constexpr int Ww = 512;
static constexpr int RAD = 4;
static constexpr float THRESH_V = 0.5f;
static constexpr int W4 = Ww / 4;          // 128 float4 per row
static constexpr int PLANE4 = Hh * W4;     // 65536 float4 per D-plane

static constexpr int TH = 4;               // output h-rows per block
static constexpr int DC = 16;              // output d-planes per block (r10 best)
static constexpr int ROWS = TH + 2 * RAD;  // 12 staged rows per plane
static constexpr int STEPS = DC + 2 * RAD; // 24 d-steps per block
static constexpr int NBLK = (Hh / TH) * (Dd / DC);  // 512 blocks (2/CU)

typedef float nf4 __attribute__((ext_vector_type(4)));  // native vec for nt-store

__device__ __forceinline__ float4 f4max(float4 a, float4 b) {
    return make_float4(fmaxf(a.x, b.x), fmaxf(a.y, b.y), fmaxf(a.z, b.z), fmaxf(a.w, b.w));
}
__device__ __forceinline__ int iclamp(int v, int lo, int hi) {
    return v < lo ? lo : (v > hi ? hi : v);
}

// DPP directions (verified r13, absmax=0): *_shr:N -> lane i reads lane i-N;
// *_shl:N -> lane i reads lane i+N.
__device__ __forceinline__ float dpp_from_left(float v) {   // lane i <- lane i-1
    int s = __float_as_int(v);
    return __int_as_float(__builtin_amdgcn_update_dpp(s, s, 0x138, 0xF, 0xF, false));
}
__device__ __forceinline__ float dpp_from_right(float v) {  // lane i <- lane i+1
    int s = __float_as_int(v);
    return __int_as_float(__builtin_amdgcn_update_dpp(s, s, 0x130, 0xF, 0xF, false));
}

// LDS-only barrier: lets cross-step global prefetch stay in flight (r10: -9 µs).
#define LDS_BARRIER() asm volatile("s_waitcnt lgkmcnt(0)\n\ts_barrier" ::: "memory")

// (512,2): CUDA-style min-blocks semantics -> 2 blocks/CU, 128-VGPR cap.
__global__ __launch_bounds__(512, 2)
void fused_nms_k(const float4* __restrict__ x4, float4* __restrict__ o4) {
    // double-buffered staging of per-plane W-max rows: 2 * 12 * 128 * 16B = 48 KB
    __shared__ float4 buf[2][ROWS * W4];

    const int tid  = threadIdx.x;
    const int lane = tid & 63;
    const int w4   = tid & (W4 - 1);              // 0..127
    const int hr   = tid >> 7;                    // 0..3
    // XCD swizzle: band = blockIdx&7 -> h-band of 64 rows stays on one XCD's L2
    const int b    = blockIdx.x;
    const int band = b & 7;
    const int rest = b >> 3;                      // 0..63
    const int ht   = band * 16 + (rest & 15);     // 0..127
    const int dc   = rest >> 4;                   // 0..3
    const int h0   = ht * TH;
    const int d0   = dc * DC;

    const bool l0  = (lane == 0);
    const bool l63 = (lane == 63);
    const int colm = w4 ? w4 - 1 : 0;
    const int colp = (w4 < W4 - 1) ? w4 + 1 : W4 - 1;
    const int hcol = l0 ? colm : colp;            // only lanes 0/63 use it

    // per-thread element offsets within a plane: 3 self rows + 3 halo slots
    int off[3], hoff[3];
#pragma unroll
    for (int k = 0; k < 3; ++k) {
        int gh = iclamp(h0 - RAD + hr + 4 * k, 0, Hh - 1);
        off[k]  = gh * W4 + w4;
        hoff[k] = gh * W4 + hcol;
    }
    const int outrow = (h0 + hr) * W4 + w4;

    // Slot ring: R[t % 8] holds H-max of plane t, overwritten AFTER use.
    float4 R[8];
    float4 L[3], HL[3];
    {   // preload plane for t=0
        const float4* pl = x4 + (size_t)iclamp(d0 - RAD, 0, Dd - 1) * PLANE4;
#pragma unroll
        for (int k = 0; k < 3; ++k) L[k] = pl[off[k]];
#pragma unroll
        for (int k = 0; k < 3; ++k) HL[k] = L[k];   // defined on all lanes
        if (l0 || l63) {
#pragma unroll
            for (int k = 0; k < 3; ++k) HL[k] = pl[hoff[k]];
        }
    }

    // 9-wide W-window max for this lane's 4 columns, neighbors via DPP.
    auto wmax_row = [&](float4 a, float4 ah) -> float4 {
        float suf3 = a.w;
        float suf2 = fmaxf(a.z, suf3);
        float suf1 = fmaxf(a.y, suf2);
        float core = fmaxf(a.x, suf1);
        float pre0 = a.x;
        float pre1 = fmaxf(pre0, a.y);
        float pre2 = fmaxf(pre1, a.z);
        float Ls0 = dpp_from_left(core), Ls1 = dpp_from_left(suf1);
        float Ls2 = dpp_from_left(suf2), Ls3 = dpp_from_left(suf3);
        float Rp0 = dpp_from_right(pre0), Rp1 = dpp_from_right(pre1);
        float Rp2 = dpp_from_right(pre2), Rp3 = dpp_from_right(core);
        // halo chains (meaningful only on lanes 0/63; discarded elsewhere)
        float hs3 = ah.w, hs2 = fmaxf(ah.z, hs3), hs1 = fmaxf(ah.y, hs2), hs0 = fmaxf(ah.x, hs1);
        float hp0 = ah.x, hp1 = fmaxf(hp0, ah.y), hp2 = fmaxf(hp1, ah.z);
        Ls0 = l0 ? hs0 : Ls0;  Ls1 = l0 ? hs1 : Ls1;
        Ls2 = l0 ? hs2 : Ls2;  Ls3 = l0 ? hs3 : Ls3;
        Rp0 = l63 ? hp0 : Rp0; Rp1 = l63 ? hp1 : Rp1;
        Rp2 = l63 ? hp2 : Rp2; Rp3 = l63 ? hs0 : Rp3;
        float4 o;
        o.x = fmaxf(Ls0, fmaxf(core, Rp0));
        o.y = fmaxf(Ls1, fmaxf(core, Rp1));
        o.z = fmaxf(Ls2, fmaxf(core, Rp2));
        o.w = fmaxf(Ls3, fmaxf(core, Rp3));
        return o;
    };

    // One d-step. slot/par/emit compile-time at every call site.
    auto body = [&](int t, int slot, int par, bool emit) {
        float4* B = buf[par];
        // (1) W-max row-by-row, ds_write IMMEDIATELY after each row so each
        //     row's DPP/halo temps die before the next row's are created
        //     (r13 kept all 3 rows + prefetch live -> 128-VGPR spill).
        {
            float4 o0 = wmax_row(L[0], HL[0]);
            B[0 * 512 + tid] = o0;
        }
        {
            float4 o1 = wmax_row(L[1], HL[1]);
            B[1 * 512 + tid] = o1;
        }
        {
            float4 o2 = wmax_row(L[2], HL[2]);
            B[2 * 512 + tid] = o2;
        }
        // (2) NOW issue this step's center + next plane's loads (after the
        //     ds_writes, before the weak barrier): prefetch regs never
        //     overlap the wmax temps, and still fly through barrier+H+emit.
        float4 cen;
        if (emit) cen = x4[(size_t)(d0 + t - 2 * RAD) * PLANE4 + outrow];
        if (t + 1 < STEPS) {
            const int gd = iclamp(d0 - RAD + t + 1, 0, Dd - 1);
            const float4* pl = x4 + (size_t)gd * PLANE4;
#pragma unroll
            for (int k = 0; k < 3; ++k) L[k] = pl[off[k]];
            if (l0 || l63) {
#pragma unroll
                for (int k = 0; k < 3; ++k) HL[k] = pl[hoff[k]];
            }
        }
        // (3) LDS-only barrier (globals NOT drained)
        LDS_BARRIER();

        // (4) H-max over 9 staged rows at this thread's column
        const float4* Bb = B + hr * W4 + w4;
        float4 m = Bb[0];
#pragma unroll
        for (int i = 1; i < 9; ++i) m = f4max(m, Bb[i * W4]);

        // (5) emit: D-window-9 = max(8 ring slots, current m)
        if (emit) {
            float4 mm = m;
#pragma unroll
            for (int i = 0; i < 8; ++i) mm = f4max(mm, R[i]);
            nf4 q;
            q.x = (cen.x > THRESH_V && cen.x == mm.x) ? cen.x : 0.0f;
            q.y = (cen.y > THRESH_V && cen.y == mm.y) ? cen.y : 0.0f;
            q.z = (cen.z > THRESH_V && cen.z == mm.z) ? cen.z : 0.0f;
            q.w = (cen.w > THRESH_V && cen.w == mm.w) ? cen.w : 0.0f;
            __builtin_nontemporal_store(
                q, (nf4*)&o4[(size_t)(d0 + t - 2 * RAD) * PLANE4 + outrow]);
        }
        R[slot] = m;   // overwrite after use
    };

    // Prologue: fill ring with planes d0-4 .. d0+3 (clamped), no outputs.
#pragma unroll
    for (int t = 0; t < 8; ++t) body(t, t, t & 1, false);
    // Main: 16 emitting steps, unroll 8 so slot indices are static.
    for (int tb = 8; tb < STEPS; tb += 8) {
#pragma unroll
        for (int j = 0; j < 8; ++j) body(tb + j, j, j & 1, true);
    }
}

extern "C" void kernel_launch(void* const* d_in, const int* in_sizes, int n_in,
                              void* d_out, int out_size, void* d_ws, size_t ws_size,
                              hipStream_t stream) {
    const float4* x4 = (const float4*)d_in[0];
    float4* out4 = (float4*)d_out;
    (void)d_ws; (void)ws_size; (void)in_sizes; (void)n_in; (void)out_size;
    fused_nms_k<<<dim3(NBLK), dim3(512), 0, stream>>>(x4, out4);
}